// Round 7
// baseline (264.765 us; speedup 1.0000x reference)
//
#include <hip/hip_runtime.h>
#include <hip/hip_bf16.h>
#include <stdint.h>

// ---------------------------------------------------------------------------
// BondPoolingLayer: out[e] = MLP(cat(h[src],h[dst])) + MLP(cat(h[dst],h[src]))
// MLP: 256 ->(W1,b1,relu) 128 ->(W2,b2,relu) 128 ->(W3,b3) 2
//
// P[n,0:128] = h[n] @ W1_top ; P[n,128:256] = h[n] @ W1_bot + b1   (bf16)
//   fwd layer1 preact = P[s,0:128] + P[d,128:256]
//   rev layer1 preact = P[d,0:128] + P[s,128:256]
//
// R12 = R9 node_proj (locked: ~65us) + barrier-free LDS-free edge_mlp.
//  - R11 counters (edge finally in top-5): 66.6us, Occ 21%, all pipes idle,
//    FETCH 107MB => BW floor ~17us => latency-bound with headroom.
//  - W2t is 32KB read-only, identical for ALL blocks => L2-resident on
//    every XCD. Staging it to LDS is pure overhead (guide common-mistake
//    #7): every block pays stage + barrier before any MFMA, coupling all
//    waves to the slowest gather.
//  - Fix: no __shared__, no __syncthreads. B-fragments read straight from
//    W2t (L2 broadcast); epilogue consts (W3,b2) reloaded from L2 per pass.
//    256-thr blocks (4 waves x 16 edges): with LDS=0, occupancy is
//    reg-bound (~116 unified => 16 waves/CU) as 4 INDEPENDENT blocks.
//    Every wave: 16 gathers in flight -> convert -> MFMA -> store,
//    fully decoupled => latency overlaps across 16 waves/CU.
//  - (256,2) not a 128-cap: R6 proved caps near the live-set spill; R11
//    proved straight-line code stays lean (84 VGPR) without a cap.
// ---------------------------------------------------------------------------

typedef __attribute__((ext_vector_type(8))) short bf16x8;
typedef __attribute__((ext_vector_type(4))) float f32x4;

__device__ __forceinline__ float bf2f(unsigned u16) {
    union { unsigned u; float f; } v; v.u = u16 << 16;
    return v.f;
}
__device__ __forceinline__ unsigned short f2bf(float f) {
    union { float f; unsigned u; } v; v.f = f;
    unsigned u = v.u;
    unsigned r = u + 0x7FFFu + ((u >> 16) & 1u);   // RNE
    return (unsigned short)(r >> 16);
}

// LDS swizzle: tiles are [rows][128 bf16], chunk = 8 bf16 (16B), 16 chunks/row.
__device__ __forceinline__ int swz(int f, int c) {
    return f * 128 + ((c ^ (f & 7)) << 3);
}

// 8 consecutive fp32 -> bf16x8 fragment (packed RNE cvt)
__device__ __forceinline__ bf16x8 cvt8(const float* p) {
    float4 x = *(const float4*)p;
    float4 y = *(const float4*)(p + 4);
    union { bf16x8 v; __hip_bfloat162 h[4]; } R;
    R.h[0] = __float22bfloat162_rn(float2{x.x, x.y});
    R.h[1] = __float22bfloat162_rn(float2{x.z, x.w});
    R.h[2] = __float22bfloat162_rn(float2{y.x, y.y});
    R.h[3] = __float22bfloat162_rn(float2{y.z, y.w});
    return R.v;
}

// elementwise relu(a+b) over 8 bf16 pairs (fp32 math), repacked to bf16x8
__device__ __forceinline__ bf16x8 addrelu8(uint4 a, uint4 b) {
    union { uint4 v; unsigned u[4]; } A, B;
    A.v = a; B.v = b;
    union { bf16x8 v; __hip_bfloat162 h[4]; } R;
#pragma unroll
    for (int i = 0; i < 4; ++i) {
        float a0 = bf2f(A.u[i] & 0xFFFFu), a1 = bf2f(A.u[i] >> 16);
        float b0 = bf2f(B.u[i] & 0xFFFFu), b1 = bf2f(B.u[i] >> 16);
        R.h[i] = __float22bfloat162_rn(float2{fmaxf(a0 + b0, 0.f),
                                              fmaxf(a1 + b1, 0.f)});
    }
    return R.v;
}

#define MFMA(a, b, c) __builtin_amdgcn_mfma_f32_16x16x32_bf16((a), (b), (c), 0, 0, 0)

// ---------------------------------------------------------------------------
// Kernel 0: weight prep (bf16 transposes, plain row-major).
// ---------------------------------------------------------------------------
__global__ void prep_weights(const float* __restrict__ W1,
                             const float* __restrict__ W2,
                             unsigned short* __restrict__ W1t,
                             unsigned short* __restrict__ W2t) {
    int idx = blockIdx.x * 256 + threadIdx.x;
    if (idx < 256 * 128) {
        int j = idx >> 7, k = idx & 127;
        float v = (j < 128) ? W1[k * 128 + j] : W1[(k + 128) * 128 + (j - 128)];
        W1t[idx] = f2bf(v);
    } else {
        int i2 = idx - 256 * 128;
        if (i2 < 128 * 128) {
            int n = i2 >> 7, k = i2 & 127;
            W2t[i2] = f2bf(W2[k * 128 + n]);
        }
    }
}

// ---------------------------------------------------------------------------
// Kernel A: node projection (byte-identical to R9, locked). Per-tile blocks;
// wave = 16 nodes x 256 features; coalesced LDS-bounce epilogue.
// ---------------------------------------------------------------------------
__global__ __launch_bounds__(512, 2) void node_proj(
    const float* __restrict__ h, const unsigned short* __restrict__ W1t,
    const float* __restrict__ b1, unsigned short* __restrict__ P, int nodes) {
    __shared__ unsigned short W1s[256 * 128];   // reused as output staging

    int t = threadIdx.x;
    int lane = t & 63;
    int wv = t >> 6;
    int ml = lane & 15, quad = lane >> 4;

    // stage W1s: thread t -> row t>>1, 8 chunks (swizzled)
    {
        int r = t >> 1, half = t & 1;
        const uint4* srcp = (const uint4*)(W1t + (size_t)r * 128 + half * 64);
#pragma unroll
        for (int i = 0; i < 8; ++i)
            *(uint4*)(W1s + swz(r, half * 8 + i)) = srcp[i];
    }

    // prefetch + convert h for this wave's 16 nodes (B-operand: n = ml)
    int node = blockIdx.x * 128 + wv * 16 + ml;
    int nodeL = (node < nodes) ? node : (nodes - 1);
    const float* hrow = h + (size_t)nodeL * 128;
    bf16x8 bfrag[4];
#pragma unroll
    for (int kk = 0; kk < 4; ++kk)
        bfrag[kk] = cvt8(hrow + kk * 32 + quad * 8);

    __syncthreads();   // W1s ready

    f32x4 acc[16] = {};
#pragma unroll
    for (int kk = 0; kk < 4; ++kk) {
#pragma unroll
        for (int ct = 0; ct < 16; ++ct) {
            bf16x8 afrag = *(const bf16x8*)(W1s + swz(ct * 16 + ml, kk * 4 + quad));
            acc[ct] = MFMA(afrag, bfrag[kk], acc[ct]);
        }
    }

    __syncthreads();   // all waves done READING W1s; safe to overwrite

    // write acc -> LDS staging. Row = wv*16+ml (512B), 16B chunks XOR-swizzled
    // by row so the linear readout below is bank-spread.
    {
        unsigned short* orow = W1s + (wv * 16 + ml) * 256;
#pragma unroll
        for (int ct = 0; ct < 16; ++ct) {
            int fbase = ct * 16 + quad * 4;
            float v0 = acc[ct][0], v1 = acc[ct][1];
            float v2 = acc[ct][2], v3 = acc[ct][3];
            if (fbase >= 128) {
                float4 bv = *(const float4*)(b1 + (fbase - 128));
                v0 += bv.x; v1 += bv.y; v2 += bv.z; v3 += bv.w;
            }
            union { uint2 u; __hip_bfloat162 h2[2]; } o;
            o.h2[0] = __float22bfloat162_rn(float2{v0, v1});
            o.h2[1] = __float22bfloat162_rn(float2{v2, v3});
            int c = ct * 2 + (quad >> 1);          // 16B chunk index in row
            *(uint2*)(orow + ((c ^ ml) << 3) + ((quad & 1) << 2)) = o.u;
        }
    }
    __syncthreads();   // staging ready

    // coalesced readout + store: per thread 8 x dwordx4; per wave-instr 1KB
    // linear. Block's P region (128 rows x 512B) is contiguous.
    {
        size_t pbase = (size_t)blockIdx.x * (128 * 256);
        int nbase = blockIdx.x * 128;
#pragma unroll
        for (int j = 0; j < 8; ++j) {
            int off = wv * 8192 + j * 1024 + lane * 16;   // byte offset in tile
            int row = off >> 9;
            int c = (off & 511) >> 4;
            uint4 v = *(const uint4*)(W1s + row * 256 + ((c ^ (row & 15)) << 3));
            if (nbase + row < nodes)
                *(uint4*)(P + pbase + (off >> 1)) = v;
        }
    }
}

// ---------------------------------------------------------------------------
// Kernel B: per-edge MLP. R12: NO LDS, NO barriers. 256 thr = 4 waves = 64
// edges; each wave fully independent. W2t B-fragments + epilogue consts read
// straight from L2 (32KB, resident on all XCDs). 16 gathers batched up-front.
// ---------------------------------------------------------------------------
__global__ __launch_bounds__(256, 2) void edge_mlp(
    const unsigned short* __restrict__ P, const int* __restrict__ src,
    const int* __restrict__ dst, const unsigned short* __restrict__ W2t,
    const float* __restrict__ b2, const float* __restrict__ W3,
    const float* __restrict__ b3, float* __restrict__ out, int E) {
    int t = threadIdx.x;
    int lane = t & 63;
    int wv = t >> 6;                 // 0..3
    int ml = lane & 15, quad = lane >> 4;

    // issue ALL 16 gather loads before any conversion (max MLP)
    int e = blockIdx.x * 64 + wv * 16 + ml;
    int ec = (e < E) ? e : (E - 1);
    int si = src[ec], di = dst[ec];
    const unsigned short* Ps = P + (size_t)si * 256;
    const unsigned short* Pd = P + (size_t)di * 256;

    uint4 slo0, slo1, slo2, slo3, shi0, shi1, shi2, shi3;
    uint4 dlo0, dlo1, dlo2, dlo3, dhi0, dhi1, dhi2, dhi3;
    {
        int ko = quad * 8;
        slo0 = *(const uint4*)(Ps + ko);       slo1 = *(const uint4*)(Ps + 32 + ko);
        slo2 = *(const uint4*)(Ps + 64 + ko);  slo3 = *(const uint4*)(Ps + 96 + ko);
        shi0 = *(const uint4*)(Ps + 128 + ko); shi1 = *(const uint4*)(Ps + 160 + ko);
        shi2 = *(const uint4*)(Ps + 192 + ko); shi3 = *(const uint4*)(Ps + 224 + ko);
        dlo0 = *(const uint4*)(Pd + ko);       dlo1 = *(const uint4*)(Pd + 32 + ko);
        dlo2 = *(const uint4*)(Pd + 64 + ko);  dlo3 = *(const uint4*)(Pd + 96 + ko);
        dhi0 = *(const uint4*)(Pd + 128 + ko); dhi1 = *(const uint4*)(Pd + 160 + ko);
        dhi2 = *(const uint4*)(Pd + 192 + ko); dhi3 = *(const uint4*)(Pd + 224 + ko);
    }

    // convert; the 16 gather temps die here, afw/arv (32 regs) carry forward
    bf16x8 afw[4], arv[4];
    afw[0] = addrelu8(slo0, dhi0); arv[0] = addrelu8(dlo0, shi0);
    afw[1] = addrelu8(slo1, dhi1); arv[1] = addrelu8(dlo1, shi1);
    afw[2] = addrelu8(slo2, dhi2); arv[2] = addrelu8(dlo2, shi2);
    afw[3] = addrelu8(slo3, dhi3); arv[3] = addrelu8(dlo3, shi3);

    float p0[4] = {0.f, 0.f, 0.f, 0.f};
    float p1[4] = {0.f, 0.f, 0.f, 0.f};

    // ---- pass fwd: acc[8]; B-fragments straight from W2t (L2) ----
    {
        f32x4 acc[8] = {};
#pragma unroll
        for (int kk = 0; kk < 4; ++kk) {
#pragma unroll
            for (int ct = 0; ct < 8; ++ct) {
                bf16x8 bfrag = *(const bf16x8*)(W2t + (size_t)(ct * 16 + ml) * 128
                                                    + (kk * 4 + quad) * 8);
                acc[ct] = MFMA(afw[kk], bfrag, acc[ct]);
            }
        }
#pragma unroll
        for (int ct = 0; ct < 8; ++ct) {
            int c = ct * 16 + ml;
            float2 w3 = *(const float2*)(W3 + c * 2);
            float bc = b2[c];
#pragma unroll
            for (int reg = 0; reg < 4; ++reg) {
                float h2 = fmaxf(acc[ct][reg] + bc, 0.f);
                p0[reg] += h2 * w3.x;
                p1[reg] += h2 * w3.y;
            }
        }
    }
    // ---- pass rev ----
    {
        f32x4 acc[8] = {};
#pragma unroll
        for (int kk = 0; kk < 4; ++kk) {
#pragma unroll
            for (int ct = 0; ct < 8; ++ct) {
                bf16x8 bfrag = *(const bf16x8*)(W2t + (size_t)(ct * 16 + ml) * 128
                                                    + (kk * 4 + quad) * 8);
                acc[ct] = MFMA(arv[kk], bfrag, acc[ct]);
            }
        }
#pragma unroll
        for (int ct = 0; ct < 8; ++ct) {
            int c = ct * 16 + ml;
            float2 w3 = *(const float2*)(W3 + c * 2);
            float bc = b2[c];
#pragma unroll
            for (int reg = 0; reg < 4; ++reg) {
                float h2 = fmaxf(acc[ct][reg] + bc, 0.f);
                p0[reg] += h2 * w3.x;
                p1[reg] += h2 * w3.y;
            }
        }
    }

    // butterfly over the 16 feature lanes
#pragma unroll
    for (int m = 1; m < 16; m <<= 1) {
#pragma unroll
        for (int reg = 0; reg < 4; ++reg) {
            p0[reg] += __shfl_xor(p0[reg], m);
            p1[reg] += __shfl_xor(p1[reg], m);
        }
    }

    // lane ml==0 writes component 0, ml==1 writes component 1
    if (ml < 2) {
        float bb = 2.f * b3[ml];
#pragma unroll
        for (int reg = 0; reg < 4; ++reg) {
            int ee = blockIdx.x * 64 + wv * 16 + quad * 4 + reg;
            if (ee < E) {
                float v = (ml == 0) ? p0[reg] : p1[reg];
                out[(size_t)ee * 2 + ml] = v + bb;
            }
        }
    }
}

// ---------------------------------------------------------------------------
extern "C" void kernel_launch(void* const* d_in, const int* in_sizes, int n_in,
                              void* d_out, int out_size, void* d_ws, size_t ws_size,
                              hipStream_t stream) {
    (void)n_in; (void)out_size; (void)ws_size;
    const float* h  = (const float*)d_in[0];
    const int*   sr = (const int*)d_in[1];
    const int*   ds = (const int*)d_in[2];
    const float* W1 = (const float*)d_in[3];
    const float* b1 = (const float*)d_in[4];
    const float* W2 = (const float*)d_in[5];
    const float* b2 = (const float*)d_in[6];
    const float* W3 = (const float*)d_in[7];
    const float* b3 = (const float*)d_in[8];
    float* out = (float*)d_out;

    int nodes = in_sizes[0] / 128;
    int E = in_sizes[1];

    unsigned short* W1t = (unsigned short*)d_ws;          // 256*128
    unsigned short* W2t = W1t + 256 * 128;                // 128*128
    unsigned short* P   = W2t + 128 * 128;                // nodes*256

    prep_weights<<<(256 * 128 + 128 * 128 + 255) / 256, 256, 0, stream>>>(W1, W2, W1t, W2t);

    int ntiles = (nodes + 127) / 128;
    node_proj<<<ntiles, 512, 0, stream>>>(h, W1t, b1, P, nodes);

    int etiles = (E + 63) / 64;
    edge_mlp<<<etiles, 256, 0, stream>>>(P, sr, ds, W2t, b2, W3, b3, out, E);
}

// Round 8
// 234.900 us; speedup vs baseline: 1.1271x; 1.1271x over previous
//
#include <hip/hip_runtime.h>
#include <hip/hip_bf16.h>
#include <stdint.h>

// ---------------------------------------------------------------------------
// BondPoolingLayer: out[e] = MLP(cat(h[src],h[dst])) + MLP(cat(h[dst],h[src]))
// MLP: 256 ->(W1,b1,relu) 128 ->(W2,b2,relu) 128 ->(W3,b3) 2
//
// P[n,0:128] = h[n] @ W1_top ; P[n,128:256] = h[n] @ W1_bot + b1   (bf16)
//   fwd layer1 preact = P[s,0:128] + P[d,128:256]
//   rev layer1 preact = P[d,0:128] + P[s,128:256]
//
// R13 = consolidation of best-of-proven + one free barrier removal.
//  - R12 post-mortem: L2-direct MFMA B-fragments REGRESSED edge 67->89us
//    (vmem latency on the MFMA critical path + contention with gathers).
//    LDS-staged W2 is correct; reverted to R11-edge verbatim (66.6us, 84
//    VGPR). Cross-round ledger: edge = 65-67us at 170 AND 95 regs => bound
//    by random-row gather throughput (~3.4 TB/s mixed L3/HBM), not occupancy.
//  - node_proj: R9 structure, barrier #3 dropped. The LDS bounce is
//    wave-symmetric (each wave writes rows wv*16..wv*16+15 and reads back
//    exactly those rows), so only within-wave ds ordering is needed
//    (lgkmcnt / threadfence_block), not an all-wave barrier drain.
//  - Known floors: node ~50us (2-block/CU staged structure; restructures
//    R6/R7/R8 all regressed), edge ~65us (fabric random-gather).
// ---------------------------------------------------------------------------

typedef __attribute__((ext_vector_type(8))) short bf16x8;
typedef __attribute__((ext_vector_type(4))) float f32x4;

__device__ __forceinline__ float bf2f(unsigned u16) {
    union { unsigned u; float f; } v; v.u = u16 << 16;
    return v.f;
}
__device__ __forceinline__ unsigned short f2bf(float f) {
    union { float f; unsigned u; } v; v.f = f;
    unsigned u = v.u;
    unsigned r = u + 0x7FFFu + ((u >> 16) & 1u);   // RNE
    return (unsigned short)(r >> 16);
}

// LDS swizzle: tiles are [rows][128 bf16], chunk = 8 bf16 (16B), 16 chunks/row.
__device__ __forceinline__ int swz(int f, int c) {
    return f * 128 + ((c ^ (f & 7)) << 3);
}

// 8 consecutive fp32 -> bf16x8 fragment (packed RNE cvt)
__device__ __forceinline__ bf16x8 cvt8(const float* p) {
    float4 x = *(const float4*)p;
    float4 y = *(const float4*)(p + 4);
    union { bf16x8 v; __hip_bfloat162 h[4]; } R;
    R.h[0] = __float22bfloat162_rn(float2{x.x, x.y});
    R.h[1] = __float22bfloat162_rn(float2{x.z, x.w});
    R.h[2] = __float22bfloat162_rn(float2{y.x, y.y});
    R.h[3] = __float22bfloat162_rn(float2{y.z, y.w});
    return R.v;
}

// elementwise relu(a+b) over 8 bf16 pairs (fp32 math), repacked to bf16x8
__device__ __forceinline__ bf16x8 addrelu8(uint4 a, uint4 b) {
    union { uint4 v; unsigned u[4]; } A, B;
    A.v = a; B.v = b;
    union { bf16x8 v; __hip_bfloat162 h[4]; } R;
#pragma unroll
    for (int i = 0; i < 4; ++i) {
        float a0 = bf2f(A.u[i] & 0xFFFFu), a1 = bf2f(A.u[i] >> 16);
        float b0 = bf2f(B.u[i] & 0xFFFFu), b1 = bf2f(B.u[i] >> 16);
        R.h[i] = __float22bfloat162_rn(float2{fmaxf(a0 + b0, 0.f),
                                              fmaxf(a1 + b1, 0.f)});
    }
    return R.v;
}

#define MFMA(a, b, c) __builtin_amdgcn_mfma_f32_16x16x32_bf16((a), (b), (c), 0, 0, 0)

// ---------------------------------------------------------------------------
// Kernel 0: weight prep (bf16 transposes, plain row-major).
// ---------------------------------------------------------------------------
__global__ void prep_weights(const float* __restrict__ W1,
                             const float* __restrict__ W2,
                             unsigned short* __restrict__ W1t,
                             unsigned short* __restrict__ W2t) {
    int idx = blockIdx.x * 256 + threadIdx.x;
    if (idx < 256 * 128) {
        int j = idx >> 7, k = idx & 127;
        float v = (j < 128) ? W1[k * 128 + j] : W1[(k + 128) * 128 + (j - 128)];
        W1t[idx] = f2bf(v);
    } else {
        int i2 = idx - 256 * 128;
        if (i2 < 128 * 128) {
            int n = i2 >> 7, k = i2 & 127;
            W2t[i2] = f2bf(W2[k * 128 + n]);
        }
    }
}

// ---------------------------------------------------------------------------
// Kernel A: node projection. R9 structure; barrier #3 removed (the LDS
// bounce is wave-local: each wave writes rows wv*16..+15 and reads back
// exactly those rows, so lgkmcnt ordering within the wave suffices).
// ---------------------------------------------------------------------------
__global__ __launch_bounds__(512, 2) void node_proj(
    const float* __restrict__ h, const unsigned short* __restrict__ W1t,
    const float* __restrict__ b1, unsigned short* __restrict__ P, int nodes) {
    __shared__ unsigned short W1s[256 * 128];   // reused as output staging

    int t = threadIdx.x;
    int lane = t & 63;
    int wv = t >> 6;
    int ml = lane & 15, quad = lane >> 4;

    // stage W1s: thread t -> row t>>1, 8 chunks (swizzled)
    {
        int r = t >> 1, half = t & 1;
        const uint4* srcp = (const uint4*)(W1t + (size_t)r * 128 + half * 64);
#pragma unroll
        for (int i = 0; i < 8; ++i)
            *(uint4*)(W1s + swz(r, half * 8 + i)) = srcp[i];
    }

    // prefetch + convert h for this wave's 16 nodes (B-operand: n = ml)
    int node = blockIdx.x * 128 + wv * 16 + ml;
    int nodeL = (node < nodes) ? node : (nodes - 1);
    const float* hrow = h + (size_t)nodeL * 128;
    bf16x8 bfrag[4];
#pragma unroll
    for (int kk = 0; kk < 4; ++kk)
        bfrag[kk] = cvt8(hrow + kk * 32 + quad * 8);

    __syncthreads();   // barrier 1: W1s ready

    f32x4 acc[16] = {};
#pragma unroll
    for (int kk = 0; kk < 4; ++kk) {
#pragma unroll
        for (int ct = 0; ct < 16; ++ct) {
            bf16x8 afrag = *(const bf16x8*)(W1s + swz(ct * 16 + ml, kk * 4 + quad));
            acc[ct] = MFMA(afrag, bfrag[kk], acc[ct]);
        }
    }

    __syncthreads();   // barrier 2: all waves done READING W1s; safe to overwrite

    // write acc -> LDS staging. Row = wv*16+ml (512B), 16B chunks XOR-swizzled
    // by row so the linear readout below is bank-spread. Wave-local rows.
    {
        unsigned short* orow = W1s + (wv * 16 + ml) * 256;
#pragma unroll
        for (int ct = 0; ct < 16; ++ct) {
            int fbase = ct * 16 + quad * 4;
            float v0 = acc[ct][0], v1 = acc[ct][1];
            float v2 = acc[ct][2], v3 = acc[ct][3];
            if (fbase >= 128) {
                float4 bv = *(const float4*)(b1 + (fbase - 128));
                v0 += bv.x; v1 += bv.y; v2 += bv.z; v3 += bv.w;
            }
            union { uint2 u; __hip_bfloat162 h2[2]; } o;
            o.h2[0] = __float22bfloat162_rn(float2{v0, v1});
            o.h2[1] = __float22bfloat162_rn(float2{v2, v3});
            int c = ct * 2 + (quad >> 1);          // 16B chunk index in row
            *(uint2*)(orow + ((c ^ ml) << 3) + ((quad & 1) << 2)) = o.u;
        }
    }

    // NO barrier 3: readout below touches only this wave's own rows.
    // threadfence_block = lgkmcnt ordering for the ds_write->ds_read chain,
    // without the all-wave s_barrier + vmcnt drain.
    __threadfence_block();

    // coalesced readout + store: per thread 8 x dwordx4; per wave-instr 1KB
    // linear. Block's P region (128 rows x 512B) is contiguous.
    {
        size_t pbase = (size_t)blockIdx.x * (128 * 256);
        int nbase = blockIdx.x * 128;
#pragma unroll
        for (int j = 0; j < 8; ++j) {
            int off = wv * 8192 + j * 1024 + lane * 16;   // byte offset in tile
            int row = off >> 9;
            int c = (off & 511) >> 4;
            uint4 v = *(const uint4*)(W1s + row * 256 + ((c ^ (row & 15)) << 3));
            if (nbase + row < nodes)
                *(uint4*)(P + pbase + (off >> 1)) = v;
        }
    }
}

// ---------------------------------------------------------------------------
// Kernel B: per-edge MLP (R11 verbatim — proven 66.6us, 84 VGPR). Per-tile
// blocks, 512 thr = 8 waves = 128 edges. Sequential fwd/rev acc[8] passes;
// 16 gather loads batched before conversion; epilogue consts from LDS.
// ---------------------------------------------------------------------------
__global__ __launch_bounds__(512, 2) void edge_mlp(
    const unsigned short* __restrict__ P, const int* __restrict__ src,
    const int* __restrict__ dst, const unsigned short* __restrict__ W2t,
    const float* __restrict__ b2, const float* __restrict__ W3,
    const float* __restrict__ b3, float* __restrict__ out, int E) {
    __shared__ unsigned short W2s[128 * 128];
    __shared__ float2 cW3[128];
    __shared__ float  cb2[128];

    int t = threadIdx.x;
    int lane = t & 63;
    int wv = t >> 6;
    int ml = lane & 15, quad = lane >> 4;

    // stage W2s: thread t -> row t>>2, 4 chunks (swizzled)
    {
        int f = t >> 2, q4 = t & 3;
        const uint4* s = (const uint4*)(W2t + (size_t)f * 128 + q4 * 32);
#pragma unroll
        for (int i = 0; i < 4; ++i)
            *(uint4*)(W2s + swz(f, q4 * 4 + i)) = s[i];
    }
    if (t < 128) {
        cW3[t] = float2{W3[t * 2 + 0], W3[t * 2 + 1]};
        cb2[t] = b2[t];
    }

    // issue ALL 16 gather loads (4 rows' worth of 16B chunks) before any
    // conversion: maximizes loads-in-flight during the latency-bound phase.
    int e = blockIdx.x * 128 + wv * 16 + ml;
    int ec = (e < E) ? e : (E - 1);
    int si = src[ec], di = dst[ec];
    const unsigned short* Ps = P + (size_t)si * 256;
    const unsigned short* Pd = P + (size_t)di * 256;

    uint4 slo0, slo1, slo2, slo3, shi0, shi1, shi2, shi3;
    uint4 dlo0, dlo1, dlo2, dlo3, dhi0, dhi1, dhi2, dhi3;
    {
        int ko = quad * 8;
        slo0 = *(const uint4*)(Ps + ko);       slo1 = *(const uint4*)(Ps + 32 + ko);
        slo2 = *(const uint4*)(Ps + 64 + ko);  slo3 = *(const uint4*)(Ps + 96 + ko);
        shi0 = *(const uint4*)(Ps + 128 + ko); shi1 = *(const uint4*)(Ps + 160 + ko);
        shi2 = *(const uint4*)(Ps + 192 + ko); shi3 = *(const uint4*)(Ps + 224 + ko);
        dlo0 = *(const uint4*)(Pd + ko);       dlo1 = *(const uint4*)(Pd + 32 + ko);
        dlo2 = *(const uint4*)(Pd + 64 + ko);  dlo3 = *(const uint4*)(Pd + 96 + ko);
        dhi0 = *(const uint4*)(Pd + 128 + ko); dhi1 = *(const uint4*)(Pd + 160 + ko);
        dhi2 = *(const uint4*)(Pd + 192 + ko); dhi3 = *(const uint4*)(Pd + 224 + ko);
    }

    // convert; the 16 gather temps die here, afw/arv (32 regs) carry forward
    bf16x8 afw[4], arv[4];
    afw[0] = addrelu8(slo0, dhi0); arv[0] = addrelu8(dlo0, shi0);
    afw[1] = addrelu8(slo1, dhi1); arv[1] = addrelu8(dlo1, shi1);
    afw[2] = addrelu8(slo2, dhi2); arv[2] = addrelu8(dlo2, shi2);
    afw[3] = addrelu8(slo3, dhi3); arv[3] = addrelu8(dlo3, shi3);

    __syncthreads();   // W2s ready

    float p0[4] = {0.f, 0.f, 0.f, 0.f};
    float p1[4] = {0.f, 0.f, 0.f, 0.f};

    // ---- pass fwd: acc[8] only (32 regs) ----
    {
        f32x4 acc[8] = {};
#pragma unroll
        for (int kk = 0; kk < 4; ++kk) {
#pragma unroll
            for (int ct = 0; ct < 8; ++ct) {
                bf16x8 bfrag = *(const bf16x8*)(W2s + swz(ct * 16 + ml, kk * 4 + quad));
                acc[ct] = MFMA(afw[kk], bfrag, acc[ct]);
            }
        }
#pragma unroll
        for (int ct = 0; ct < 8; ++ct) {
            int c = ct * 16 + ml;
            float2 w3 = cW3[c];
            float bc = cb2[c];
#pragma unroll
            for (int reg = 0; reg < 4; ++reg) {
                float h2 = fmaxf(acc[ct][reg] + bc, 0.f);
                p0[reg] += h2 * w3.x;
                p1[reg] += h2 * w3.y;
            }
        }
    }
    // ---- pass rev ----
    {
        f32x4 acc[8] = {};
#pragma unroll
        for (int kk = 0; kk < 4; ++kk) {
#pragma unroll
            for (int ct = 0; ct < 8; ++ct) {
                bf16x8 bfrag = *(const bf16x8*)(W2s + swz(ct * 16 + ml, kk * 4 + quad));
                acc[ct] = MFMA(arv[kk], bfrag, acc[ct]);
            }
        }
#pragma unroll
        for (int ct = 0; ct < 8; ++ct) {
            int c = ct * 16 + ml;
            float2 w3 = cW3[c];
            float bc = cb2[c];
#pragma unroll
            for (int reg = 0; reg < 4; ++reg) {
                float h2 = fmaxf(acc[ct][reg] + bc, 0.f);
                p0[reg] += h2 * w3.x;
                p1[reg] += h2 * w3.y;
            }
        }
    }

    // butterfly over the 16 feature lanes
#pragma unroll
    for (int m = 1; m < 16; m <<= 1) {
#pragma unroll
        for (int reg = 0; reg < 4; ++reg) {
            p0[reg] += __shfl_xor(p0[reg], m);
            p1[reg] += __shfl_xor(p1[reg], m);
        }
    }

    // lane ml==0 writes component 0, ml==1 writes component 1
    if (ml < 2) {
        float bb = 2.f * b3[ml];
#pragma unroll
        for (int reg = 0; reg < 4; ++reg) {
            int ee = blockIdx.x * 128 + wv * 16 + quad * 4 + reg;
            if (ee < E) {
                float v = (ml == 0) ? p0[reg] : p1[reg];
                out[(size_t)ee * 2 + ml] = v + bb;
            }
        }
    }
}

// ---------------------------------------------------------------------------
extern "C" void kernel_launch(void* const* d_in, const int* in_sizes, int n_in,
                              void* d_out, int out_size, void* d_ws, size_t ws_size,
                              hipStream_t stream) {
    (void)n_in; (void)out_size; (void)ws_size;
    const float* h  = (const float*)d_in[0];
    const int*   sr = (const int*)d_in[1];
    const int*   ds = (const int*)d_in[2];
    const float* W1 = (const float*)d_in[3];
    const float* b1 = (const float*)d_in[4];
    const float* W2 = (const float*)d_in[5];
    const float* b2 = (const float*)d_in[6];
    const float* W3 = (const float*)d_in[7];
    const float* b3 = (const float*)d_in[8];
    float* out = (float*)d_out;

    int nodes = in_sizes[0] / 128;
    int E = in_sizes[1];

    unsigned short* W1t = (unsigned short*)d_ws;          // 256*128
    unsigned short* W2t = W1t + 256 * 128;                // 128*128
    unsigned short* P   = W2t + 128 * 128;                // nodes*256

    prep_weights<<<(256 * 128 + 128 * 128 + 255) / 256, 256, 0, stream>>>(W1, W2, W1t, W2t);

    int ntiles = (nodes + 127) / 128;
    node_proj<<<ntiles, 512, 0, stream>>>(h, W1t, b1, P, nodes);

    int etiles = (E + 127) / 128;
    edge_mlp<<<etiles, 512, 0, stream>>>(P, sr, ds, W2t, b2, W3, b3, out, E);
}

// Round 9
// 233.673 us; speedup vs baseline: 1.1331x; 1.0053x over previous
//
#include <hip/hip_runtime.h>
#include <hip/hip_bf16.h>
#include <stdint.h>

// ---------------------------------------------------------------------------
// BondPoolingLayer: out[e] = MLP(cat(h[src],h[dst])) + MLP(cat(h[dst],h[src]))
// MLP: 256 ->(W1,b1,relu) 128 ->(W2,b2,relu) 128 ->(W3,b3) 2
//
// R14: FULL FUSION. node_proj eliminated.
//  - Ledger: h row (128 f32) = 512 B = P row (256 bf16). Gathering h instead
//    of P costs IDENTICAL random-gather traffic, so the only purpose of
//    node_proj was to pre-share layer-1 work (~2.2x reuse). But MfmaUtil is
//    8% — matrix pipe is idle. Fusing layer-1 into the edge kernel deletes:
//    node_proj (~66us), the 100MB P-write + 107MB P-fetch round-trip, and
//    one launch. Added: ~2.2x layer-1 MFMA (idle-pipe cycles).
//  - Numerics: layer-1 is now ONE K=256 fp32-accum MFMA chain per edge
//    (reference's exact shape) — strictly fewer bf16 roundings than the
//    two-stage P path. absmax <= 0.03125 expected.
//  - Structure (all session-proven pieces):
//      stage W1c(64K)+W2s(32K)+consts, ONE barrier;
//      batch 16 h-gather loads -> convert (R11 pattern);
//      layer-1 fwd/rev: A=W1c-frag from LDS, B=h-frag (node_proj operand
//        order, C: col=edge(ml), row=feat(ct*16+quad*4+reg));
//      per-wave 4KB LDS bounce w/ XOR swizzle + threadfence (R9/R13) to
//        redistribute C-layout -> layer-2 A-frag layout;
//      layer-2: R11/R13 code verbatim.
//  - LDS 130KB -> 1 block/CU (8 waves). Edge proven occupancy-insensitive
//    (8 vs 16 waves identical, R5-R13); reg budget free (<=256/wave).
// ---------------------------------------------------------------------------

typedef __attribute__((ext_vector_type(8))) short bf16x8;
typedef __attribute__((ext_vector_type(4))) float f32x4;

__device__ __forceinline__ float bf2f(unsigned u16) {
    union { unsigned u; float f; } v; v.u = u16 << 16;
    return v.f;
}
__device__ __forceinline__ unsigned short f2bf(float f) {
    union { float f; unsigned u; } v; v.f = f;
    unsigned u = v.u;
    unsigned r = u + 0x7FFFu + ((u >> 16) & 1u);   // RNE
    return (unsigned short)(r >> 16);
}

// swizzles: rows of 128 bf16 (16 chunks) and 256 bf16 (32 chunks); chunk=16B.
__device__ __forceinline__ int swz(int f, int c) {       // row len 128
    return f * 128 + ((c ^ (f & 7)) << 3);
}
__device__ __forceinline__ int swzA(int f, int c) {      // row len 256
    return f * 256 + ((c ^ (f & 7)) << 3);
}

// two float4 (8 consecutive fp32) -> bf16x8 fragment (packed RNE)
__device__ __forceinline__ bf16x8 cvt8v(float4 x, float4 y) {
    union { bf16x8 v; __hip_bfloat162 h[4]; } R;
    R.h[0] = __float22bfloat162_rn(float2{x.x, x.y});
    R.h[1] = __float22bfloat162_rn(float2{x.z, x.w});
    R.h[2] = __float22bfloat162_rn(float2{y.x, y.y});
    R.h[3] = __float22bfloat162_rn(float2{y.z, y.w});
    return R.v;
}

#define MFMA(a, b, c) __builtin_amdgcn_mfma_f32_16x16x32_bf16((a), (b), (c), 0, 0, 0)

// ---------------------------------------------------------------------------
// Kernel 0: weight prep.
// W1c[j][k] (j in [0,128) out-feature, k in [0,256) concat-input) = W1[k][j]
// W2t[n][k] = W2[k][n]
// ---------------------------------------------------------------------------
__global__ void prep_weights(const float* __restrict__ W1,
                             const float* __restrict__ W2,
                             unsigned short* __restrict__ W1c,
                             unsigned short* __restrict__ W2t) {
    int idx = blockIdx.x * 256 + threadIdx.x;
    if (idx < 128 * 256) {
        int j = idx >> 8, k = idx & 255;
        W1c[idx] = f2bf(W1[k * 128 + j]);
    } else {
        int i2 = idx - 128 * 256;
        if (i2 < 128 * 128) {
            int n = i2 >> 7, k = i2 & 127;
            W2t[i2] = f2bf(W2[k * 128 + n]);
        }
    }
}

// ---------------------------------------------------------------------------
// Fused per-edge kernel. Block = 512 thr = 8 waves = 128 edges.
// Wave = 16 edges (lane ml owns edge wv*16+ml; quad = k/feature part).
// ---------------------------------------------------------------------------
__global__ __launch_bounds__(512, 1) void edge_fused(
    const float* __restrict__ h, const int* __restrict__ src,
    const int* __restrict__ dst, const unsigned short* __restrict__ W1c,
    const unsigned short* __restrict__ W2t, const float* __restrict__ b1,
    const float* __restrict__ b2, const float* __restrict__ W3,
    const float* __restrict__ b3, float* __restrict__ out, int E) {
    __shared__ unsigned short W1s[128 * 256];     // 64KB [out-feat][k=256]
    __shared__ unsigned short W2s[128 * 128];     // 32KB [out-feat][k=128]
    __shared__ unsigned short scr[8 * 16 * 128];  // 32KB: wave x 16 edges x 128 feats
    __shared__ float  cb1[128];
    __shared__ float  cb2[128];
    __shared__ float2 cW3[128];

    int t = threadIdx.x;
    int lane = t & 63;
    int wv = t >> 6;
    int ml = lane & 15, quad = lane >> 4;

    // ---- stage W1s: thread t -> row t>>2 (128 rows), 8 of 32 chunks ----
    {
        int r = t >> 2, q = t & 3;
        const uint4* s = (const uint4*)(W1c + (size_t)r * 256 + q * 64);
#pragma unroll
        for (int i = 0; i < 8; ++i)
            *(uint4*)(W1s + swzA(r, q * 8 + i)) = s[i];
    }
    // ---- stage W2s: thread t -> row t>>2, 4 of 16 chunks ----
    {
        int f = t >> 2, q4 = t & 3;
        const uint4* s = (const uint4*)(W2t + (size_t)f * 128 + q4 * 32);
#pragma unroll
        for (int i = 0; i < 4; ++i)
            *(uint4*)(W2s + swz(f, q4 * 4 + i)) = s[i];
    }
    if (t < 128) {
        cb1[t] = b1[t];
        cb2[t] = b2[t];
        cW3[t] = float2{W3[t * 2 + 0], W3[t * 2 + 1]};
    }

    // ---- batch h gathers (16 x 16B fp32 loads) BEFORE the barrier ----
    int e = blockIdx.x * 128 + wv * 16 + ml;
    int ec = (e < E) ? e : (E - 1);
    int si = src[ec], di = dst[ec];
    const float* hs = h + (size_t)si * 128;
    const float* hd = h + (size_t)di * 128;

    float4 s0a, s0b, s1a, s1b, s2a, s2b, s3a, s3b;
    float4 d0a, d0b, d1a, d1b, d2a, d2b, d3a, d3b;
    {
        int ko = quad * 8;
        s0a = *(const float4*)(hs + ko);       s0b = *(const float4*)(hs + ko + 4);
        s1a = *(const float4*)(hs + 32 + ko);  s1b = *(const float4*)(hs + 36 + ko);
        s2a = *(const float4*)(hs + 64 + ko);  s2b = *(const float4*)(hs + 68 + ko);
        s3a = *(const float4*)(hs + 96 + ko);  s3b = *(const float4*)(hs + 100 + ko);
        d0a = *(const float4*)(hd + ko);       d0b = *(const float4*)(hd + ko + 4);
        d1a = *(const float4*)(hd + 32 + ko);  d1b = *(const float4*)(hd + 36 + ko);
        d2a = *(const float4*)(hd + 64 + ko);  d2b = *(const float4*)(hd + 68 + ko);
        d3a = *(const float4*)(hd + 96 + ko);  d3b = *(const float4*)(hd + 100 + ko);
    }
    // convert: lane (ml,quad) holds h[own edge][k = kk*32 + quad*8 .. +8]
    bf16x8 hsf[4], hdf[4];
    hsf[0] = cvt8v(s0a, s0b); hsf[1] = cvt8v(s1a, s1b);
    hsf[2] = cvt8v(s2a, s2b); hsf[3] = cvt8v(s3a, s3b);
    hdf[0] = cvt8v(d0a, d0b); hdf[1] = cvt8v(d1a, d1b);
    hdf[2] = cvt8v(d2a, d2b); hdf[3] = cvt8v(d3a, d3b);

    __syncthreads();   // LDS ready; only within-wave fences from here on

    unsigned short* scrW = scr + wv * 2048;   // this wave's 16x128 scratch
    bf16x8 afw[4], arv[4];

    // ================= layer 1, fwd: preact = cat(hs,hd) @ W1 + b1 =========
    {
        f32x4 acc[8] = {};
#pragma unroll
        for (int kk = 0; kk < 4; ++kk)       // k 0..127 <- hs
#pragma unroll
            for (int ct = 0; ct < 8; ++ct)
                acc[ct] = MFMA(*(const bf16x8*)(W1s + swzA(ct * 16 + ml, kk * 4 + quad)),
                               hsf[kk], acc[ct]);
#pragma unroll
        for (int kk = 4; kk < 8; ++kk)       // k 128..255 <- hd
#pragma unroll
            for (int ct = 0; ct < 8; ++ct)
                acc[ct] = MFMA(*(const bf16x8*)(W1s + swzA(ct * 16 + ml, kk * 4 + quad)),
                               hdf[kk - 4], acc[ct]);

        // epilogue: +b1, relu, pack -> swizzled scratch (edge ml's row).
        // C layout: col = ml (edge), row = feat = ct*16 + quad*4 + reg.
#pragma unroll
        for (int ct = 0; ct < 8; ++ct) {
            int fb = ct * 16 + quad * 4;
            float4 bv = *(const float4*)(cb1 + fb);
            union { uint2 u; __hip_bfloat162 h2[2]; } o;
            o.h2[0] = __float22bfloat162_rn(float2{fmaxf(acc[ct][0] + bv.x, 0.f),
                                                   fmaxf(acc[ct][1] + bv.y, 0.f)});
            o.h2[1] = __float22bfloat162_rn(float2{fmaxf(acc[ct][2] + bv.z, 0.f),
                                                   fmaxf(acc[ct][3] + bv.w, 0.f)});
            int chunk = ct * 2 + (quad >> 1);             // fb>>3
            *(uint2*)(scrW + ml * 128 + ((chunk ^ (ml & 7)) << 3) + ((quad & 1) << 2)) = o.u;
        }
        __threadfence_block();   // within-wave ds_write -> ds_read ordering

        // read layer-2 A-frags: edge ml's feats [kk*32+quad*8 .. +8]
#pragma unroll
        for (int kk = 0; kk < 4; ++kk) {
            int chunk = kk * 4 + quad;
            afw[kk] = *(const bf16x8*)(scrW + ml * 128 + ((chunk ^ (ml & 7)) << 3));
        }
    }

    // ================= layer 1, rev: preact = cat(hd,hs) @ W1 + b1 =========
    {
        f32x4 acc[8] = {};
#pragma unroll
        for (int kk = 0; kk < 4; ++kk)       // k 0..127 <- hd
#pragma unroll
            for (int ct = 0; ct < 8; ++ct)
                acc[ct] = MFMA(*(const bf16x8*)(W1s + swzA(ct * 16 + ml, kk * 4 + quad)),
                               hdf[kk], acc[ct]);
#pragma unroll
        for (int kk = 4; kk < 8; ++kk)       // k 128..255 <- hs
#pragma unroll
            for (int ct = 0; ct < 8; ++ct)
                acc[ct] = MFMA(*(const bf16x8*)(W1s + swzA(ct * 16 + ml, kk * 4 + quad)),
                               hsf[kk - 4], acc[ct]);

#pragma unroll
        for (int ct = 0; ct < 8; ++ct) {
            int fb = ct * 16 + quad * 4;
            float4 bv = *(const float4*)(cb1 + fb);
            union { uint2 u; __hip_bfloat162 h2[2]; } o;
            o.h2[0] = __float22bfloat162_rn(float2{fmaxf(acc[ct][0] + bv.x, 0.f),
                                                   fmaxf(acc[ct][1] + bv.y, 0.f)});
            o.h2[1] = __float22bfloat162_rn(float2{fmaxf(acc[ct][2] + bv.z, 0.f),
                                                   fmaxf(acc[ct][3] + bv.w, 0.f)});
            int chunk = ct * 2 + (quad >> 1);
            *(uint2*)(scrW + ml * 128 + ((chunk ^ (ml & 7)) << 3) + ((quad & 1) << 2)) = o.u;
        }
        __threadfence_block();

#pragma unroll
        for (int kk = 0; kk < 4; ++kk) {
            int chunk = kk * 4 + quad;
            arv[kk] = *(const bf16x8*)(scrW + ml * 128 + ((chunk ^ (ml & 7)) << 3));
        }
    }

    // ================= layer 2 + 3 (R11/R13 code verbatim) ==================
    float p0[4] = {0.f, 0.f, 0.f, 0.f};
    float p1[4] = {0.f, 0.f, 0.f, 0.f};

    // ---- pass fwd ----
    {
        f32x4 acc[8] = {};
#pragma unroll
        for (int kk = 0; kk < 4; ++kk)
#pragma unroll
            for (int ct = 0; ct < 8; ++ct)
                acc[ct] = MFMA(afw[kk],
                               *(const bf16x8*)(W2s + swz(ct * 16 + ml, kk * 4 + quad)),
                               acc[ct]);
#pragma unroll
        for (int ct = 0; ct < 8; ++ct) {
            int c = ct * 16 + ml;
            float2 w3 = cW3[c];
            float bc = cb2[c];
#pragma unroll
            for (int reg = 0; reg < 4; ++reg) {
                float h2 = fmaxf(acc[ct][reg] + bc, 0.f);
                p0[reg] += h2 * w3.x;
                p1[reg] += h2 * w3.y;
            }
        }
    }
    // ---- pass rev ----
    {
        f32x4 acc[8] = {};
#pragma unroll
        for (int kk = 0; kk < 4; ++kk)
#pragma unroll
            for (int ct = 0; ct < 8; ++ct)
                acc[ct] = MFMA(arv[kk],
                               *(const bf16x8*)(W2s + swz(ct * 16 + ml, kk * 4 + quad)),
                               acc[ct]);
#pragma unroll
        for (int ct = 0; ct < 8; ++ct) {
            int c = ct * 16 + ml;
            float2 w3 = cW3[c];
            float bc = cb2[c];
#pragma unroll
            for (int reg = 0; reg < 4; ++reg) {
                float h2 = fmaxf(acc[ct][reg] + bc, 0.f);
                p0[reg] += h2 * w3.x;
                p1[reg] += h2 * w3.y;
            }
        }
    }

    // butterfly over the 16 feature lanes
#pragma unroll
    for (int m = 1; m < 16; m <<= 1) {
#pragma unroll
        for (int reg = 0; reg < 4; ++reg) {
            p0[reg] += __shfl_xor(p0[reg], m);
            p1[reg] += __shfl_xor(p1[reg], m);
        }
    }

    // lane ml==0 writes component 0, ml==1 writes component 1
    if (ml < 2) {
        float bb = 2.f * b3[ml];
#pragma unroll
        for (int reg = 0; reg < 4; ++reg) {
            int ee = blockIdx.x * 128 + wv * 16 + quad * 4 + reg;
            if (ee < E) {
                float v = (ml == 0) ? p0[reg] : p1[reg];
                out[(size_t)ee * 2 + ml] = v + bb;
            }
        }
    }
}

// ---------------------------------------------------------------------------
extern "C" void kernel_launch(void* const* d_in, const int* in_sizes, int n_in,
                              void* d_out, int out_size, void* d_ws, size_t ws_size,
                              hipStream_t stream) {
    (void)n_in; (void)out_size; (void)ws_size;
    const float* h  = (const float*)d_in[0];
    const int*   sr = (const int*)d_in[1];
    const int*   ds = (const int*)d_in[2];
    const float* W1 = (const float*)d_in[3];
    const float* b1 = (const float*)d_in[4];
    const float* W2 = (const float*)d_in[5];
    const float* b2 = (const float*)d_in[6];
    const float* W3 = (const float*)d_in[7];
    const float* b3 = (const float*)d_in[8];
    float* out = (float*)d_out;

    int E = in_sizes[1];

    unsigned short* W1c = (unsigned short*)d_ws;          // 128*256
    unsigned short* W2t = W1c + 128 * 256;                // 128*128

    prep_weights<<<(128 * 256 + 128 * 128 + 255) / 256, 256, 0, stream>>>(W1, W2, W1c, W2t);

    int etiles = (E + 127) / 128;
    edge_fused<<<etiles, 512, 0, stream>>>(h, sr, ds, W1c, W2t, b1, b2, W3, b3, out, E);
}

// Round 10
// 227.169 us; speedup vs baseline: 1.1655x; 1.0286x over previous
//
#include <hip/hip_runtime.h>
#include <hip/hip_bf16.h>
#include <stdint.h>

// ---------------------------------------------------------------------------
// BondPoolingLayer: out[e] = MLP(cat(h[src],h[dst])) + MLP(cat(h[dst],h[src]))
// MLP: 256 ->(W1,b1,relu) 128 ->(W2,b2,relu) 128 ->(W3,b3) 2
//
// R15 = R14 fused kernel + fwd/rev PASS FUSION (halve weight LDS reads).
//  - R14 counters: 113.8us, LDS_BANK_CONFLICT 13.2M (6x edge_mlp). Port
//    arithmetic: 244 DS ops/lane -> ~103K LDS-port cycles/CU ~= 43us busy,
//    half of it conflict cycles. At 1 block/CU (133KB LDS) nothing hides it.
//  - Key: fwd and rev passes read IDENTICAL weight fragments. Fuse: read
//    each W1s/W2s fragment once, issue two MFMAs (accf with hsf, accr with
//    hdf; swapped for k>=128). W1s reads 128->64, W2s 64->32, DS ops -40%.
//    Register cost accf+accr = 64 live — fine at 2 waves/SIMD (256 cap).
//  - Epilogue folds accf/accr straight into p0/p1 (output sums fwd+rev).
//  - Unchanged (R14-proven): batch h-gathers, scr bounce (two rounds,
//    back-to-back), swizzles, consts, C-layout, launcher.
// ---------------------------------------------------------------------------

typedef __attribute__((ext_vector_type(8))) short bf16x8;
typedef __attribute__((ext_vector_type(4))) float f32x4;

__device__ __forceinline__ float bf2f(unsigned u16) {
    union { unsigned u; float f; } v; v.u = u16 << 16;
    return v.f;
}
__device__ __forceinline__ unsigned short f2bf(float f) {
    union { float f; unsigned u; } v; v.f = f;
    unsigned u = v.u;
    unsigned r = u + 0x7FFFu + ((u >> 16) & 1u);   // RNE
    return (unsigned short)(r >> 16);
}

// swizzles: rows of 128 bf16 (16 chunks) and 256 bf16 (32 chunks); chunk=16B.
__device__ __forceinline__ int swz(int f, int c) {       // row len 128
    return f * 128 + ((c ^ (f & 7)) << 3);
}
__device__ __forceinline__ int swzA(int f, int c) {      // row len 256
    return f * 256 + ((c ^ (f & 7)) << 3);
}

// two float4 (8 consecutive fp32) -> bf16x8 fragment (packed RNE)
__device__ __forceinline__ bf16x8 cvt8v(float4 x, float4 y) {
    union { bf16x8 v; __hip_bfloat162 h[4]; } R;
    R.h[0] = __float22bfloat162_rn(float2{x.x, x.y});
    R.h[1] = __float22bfloat162_rn(float2{x.z, x.w});
    R.h[2] = __float22bfloat162_rn(float2{y.x, y.y});
    R.h[3] = __float22bfloat162_rn(float2{y.z, y.w});
    return R.v;
}

#define MFMA(a, b, c) __builtin_amdgcn_mfma_f32_16x16x32_bf16((a), (b), (c), 0, 0, 0)

// ---------------------------------------------------------------------------
// Kernel 0: weight prep.
// W1c[j][k] (j in [0,128) out-feature, k in [0,256) concat-input) = W1[k][j]
// W2t[n][k] = W2[k][n]
// ---------------------------------------------------------------------------
__global__ void prep_weights(const float* __restrict__ W1,
                             const float* __restrict__ W2,
                             unsigned short* __restrict__ W1c,
                             unsigned short* __restrict__ W2t) {
    int idx = blockIdx.x * 256 + threadIdx.x;
    if (idx < 128 * 256) {
        int j = idx >> 8, k = idx & 255;
        W1c[idx] = f2bf(W1[k * 128 + j]);
    } else {
        int i2 = idx - 128 * 256;
        if (i2 < 128 * 128) {
            int n = i2 >> 7, k = i2 & 127;
            W2t[i2] = f2bf(W2[k * 128 + n]);
        }
    }
}

// ---------------------------------------------------------------------------
// Fused per-edge kernel. Block = 512 thr = 8 waves = 128 edges.
// Wave = 16 edges (lane ml owns edge wv*16+ml; quad = k/feature part).
// ---------------------------------------------------------------------------
__global__ __launch_bounds__(512, 1) void edge_fused(
    const float* __restrict__ h, const int* __restrict__ src,
    const int* __restrict__ dst, const unsigned short* __restrict__ W1c,
    const unsigned short* __restrict__ W2t, const float* __restrict__ b1,
    const float* __restrict__ b2, const float* __restrict__ W3,
    const float* __restrict__ b3, float* __restrict__ out, int E) {
    __shared__ unsigned short W1s[128 * 256];     // 64KB [out-feat][k=256]
    __shared__ unsigned short W2s[128 * 128];     // 32KB [out-feat][k=128]
    __shared__ unsigned short scr[8 * 16 * 128];  // 32KB: wave x 16 edges x 128 feats
    __shared__ float  cb1[128];
    __shared__ float  cb2[128];
    __shared__ float2 cW3[128];

    int t = threadIdx.x;
    int lane = t & 63;
    int wv = t >> 6;
    int ml = lane & 15, quad = lane >> 4;

    // ---- stage W1s: thread t -> row t>>2 (128 rows), 8 of 32 chunks ----
    {
        int r = t >> 2, q = t & 3;
        const uint4* s = (const uint4*)(W1c + (size_t)r * 256 + q * 64);
#pragma unroll
        for (int i = 0; i < 8; ++i)
            *(uint4*)(W1s + swzA(r, q * 8 + i)) = s[i];
    }
    // ---- stage W2s: thread t -> row t>>2, 4 of 16 chunks ----
    {
        int f = t >> 2, q4 = t & 3;
        const uint4* s = (const uint4*)(W2t + (size_t)f * 128 + q4 * 32);
#pragma unroll
        for (int i = 0; i < 4; ++i)
            *(uint4*)(W2s + swz(f, q4 * 4 + i)) = s[i];
    }
    if (t < 128) {
        cb1[t] = b1[t];
        cb2[t] = b2[t];
        cW3[t] = float2{W3[t * 2 + 0], W3[t * 2 + 1]};
    }

    // ---- batch h gathers (16 x 16B fp32 loads) BEFORE the barrier ----
    int e = blockIdx.x * 128 + wv * 16 + ml;
    int ec = (e < E) ? e : (E - 1);
    int si = src[ec], di = dst[ec];
    const float* hs = h + (size_t)si * 128;
    const float* hd = h + (size_t)di * 128;

    float4 s0a, s0b, s1a, s1b, s2a, s2b, s3a, s3b;
    float4 d0a, d0b, d1a, d1b, d2a, d2b, d3a, d3b;
    {
        int ko = quad * 8;
        s0a = *(const float4*)(hs + ko);       s0b = *(const float4*)(hs + ko + 4);
        s1a = *(const float4*)(hs + 32 + ko);  s1b = *(const float4*)(hs + 36 + ko);
        s2a = *(const float4*)(hs + 64 + ko);  s2b = *(const float4*)(hs + 68 + ko);
        s3a = *(const float4*)(hs + 96 + ko);  s3b = *(const float4*)(hs + 100 + ko);
        d0a = *(const float4*)(hd + ko);       d0b = *(const float4*)(hd + ko + 4);
        d1a = *(const float4*)(hd + 32 + ko);  d1b = *(const float4*)(hd + 36 + ko);
        d2a = *(const float4*)(hd + 64 + ko);  d2b = *(const float4*)(hd + 68 + ko);
        d3a = *(const float4*)(hd + 96 + ko);  d3b = *(const float4*)(hd + 100 + ko);
    }
    // convert: lane (ml,quad) holds h[own edge][k = kk*32 + quad*8 .. +8]
    bf16x8 hsf[4], hdf[4];
    hsf[0] = cvt8v(s0a, s0b); hsf[1] = cvt8v(s1a, s1b);
    hsf[2] = cvt8v(s2a, s2b); hsf[3] = cvt8v(s3a, s3b);
    hdf[0] = cvt8v(d0a, d0b); hdf[1] = cvt8v(d1a, d1b);
    hdf[2] = cvt8v(d2a, d2b); hdf[3] = cvt8v(d3a, d3b);

    __syncthreads();   // LDS ready; only within-wave fences from here on

    unsigned short* scrW = scr + wv * 2048;   // this wave's 16x128 scratch
    bf16x8 afw[4], arv[4];

    // ========== layer 1, FUSED fwd+rev: each W1s fragment read ONCE ========
    {
        f32x4 accf[8] = {}, accr[8] = {};
#pragma unroll
        for (int kk = 0; kk < 4; ++kk) {     // k 0..127: fwd<-hs, rev<-hd
#pragma unroll
            for (int ct = 0; ct < 8; ++ct) {
                bf16x8 a = *(const bf16x8*)(W1s + swzA(ct * 16 + ml, kk * 4 + quad));
                accf[ct] = MFMA(a, hsf[kk], accf[ct]);
                accr[ct] = MFMA(a, hdf[kk], accr[ct]);
            }
        }
#pragma unroll
        for (int kk = 4; kk < 8; ++kk) {     // k 128..255: fwd<-hd, rev<-hs
#pragma unroll
            for (int ct = 0; ct < 8; ++ct) {
                bf16x8 a = *(const bf16x8*)(W1s + swzA(ct * 16 + ml, kk * 4 + quad));
                accf[ct] = MFMA(a, hdf[kk - 4], accf[ct]);
                accr[ct] = MFMA(a, hsf[kk - 4], accr[ct]);
            }
        }

        // ---- bounce round 1 (fwd): +b1, relu, pack -> swizzled scratch ----
        // C layout: col = ml (edge), row = feat = ct*16 + quad*4 + reg.
#pragma unroll
        for (int ct = 0; ct < 8; ++ct) {
            int fb = ct * 16 + quad * 4;
            float4 bv = *(const float4*)(cb1 + fb);
            union { uint2 u; __hip_bfloat162 h2[2]; } o;
            o.h2[0] = __float22bfloat162_rn(float2{fmaxf(accf[ct][0] + bv.x, 0.f),
                                                   fmaxf(accf[ct][1] + bv.y, 0.f)});
            o.h2[1] = __float22bfloat162_rn(float2{fmaxf(accf[ct][2] + bv.z, 0.f),
                                                   fmaxf(accf[ct][3] + bv.w, 0.f)});
            int chunk = ct * 2 + (quad >> 1);             // fb>>3
            *(uint2*)(scrW + ml * 128 + ((chunk ^ (ml & 7)) << 3) + ((quad & 1) << 2)) = o.u;
        }
        __threadfence_block();   // within-wave ds_write -> ds_read ordering
#pragma unroll
        for (int kk = 0; kk < 4; ++kk) {
            int chunk = kk * 4 + quad;
            afw[kk] = *(const bf16x8*)(scrW + ml * 128 + ((chunk ^ (ml & 7)) << 3));
        }
        __threadfence_block();   // round-1 reads ordered before round-2 writes

        // ---- bounce round 2 (rev) ----
#pragma unroll
        for (int ct = 0; ct < 8; ++ct) {
            int fb = ct * 16 + quad * 4;
            float4 bv = *(const float4*)(cb1 + fb);
            union { uint2 u; __hip_bfloat162 h2[2]; } o;
            o.h2[0] = __float22bfloat162_rn(float2{fmaxf(accr[ct][0] + bv.x, 0.f),
                                                   fmaxf(accr[ct][1] + bv.y, 0.f)});
            o.h2[1] = __float22bfloat162_rn(float2{fmaxf(accr[ct][2] + bv.z, 0.f),
                                                   fmaxf(accr[ct][3] + bv.w, 0.f)});
            int chunk = ct * 2 + (quad >> 1);
            *(uint2*)(scrW + ml * 128 + ((chunk ^ (ml & 7)) << 3) + ((quad & 1) << 2)) = o.u;
        }
        __threadfence_block();
#pragma unroll
        for (int kk = 0; kk < 4; ++kk) {
            int chunk = kk * 4 + quad;
            arv[kk] = *(const bf16x8*)(scrW + ml * 128 + ((chunk ^ (ml & 7)) << 3));
        }
    }

    // ========== layer 2+3, FUSED fwd+rev: each W2s fragment read ONCE ======
    float p0[4] = {0.f, 0.f, 0.f, 0.f};
    float p1[4] = {0.f, 0.f, 0.f, 0.f};
    {
        f32x4 acc2f[8] = {}, acc2r[8] = {};
#pragma unroll
        for (int kk = 0; kk < 4; ++kk) {
#pragma unroll
            for (int ct = 0; ct < 8; ++ct) {
                bf16x8 b = *(const bf16x8*)(W2s + swz(ct * 16 + ml, kk * 4 + quad));
                acc2f[ct] = MFMA(afw[kk], b, acc2f[ct]);
                acc2r[ct] = MFMA(arv[kk], b, acc2r[ct]);
            }
        }
        // epilogue: +b2, relu, dot W3 columns; fwd+rev folded into p0/p1
#pragma unroll
        for (int ct = 0; ct < 8; ++ct) {
            int c = ct * 16 + ml;
            float2 w3 = cW3[c];
            float bc = cb2[c];
#pragma unroll
            for (int reg = 0; reg < 4; ++reg) {
                float hf = fmaxf(acc2f[ct][reg] + bc, 0.f);
                float hr = fmaxf(acc2r[ct][reg] + bc, 0.f);
                p0[reg] += (hf + hr) * w3.x;
                p1[reg] += (hf + hr) * w3.y;
            }
        }
    }

    // butterfly over the 16 feature lanes
#pragma unroll
    for (int m = 1; m < 16; m <<= 1) {
#pragma unroll
        for (int reg = 0; reg < 4; ++reg) {
            p0[reg] += __shfl_xor(p0[reg], m);
            p1[reg] += __shfl_xor(p1[reg], m);
        }
    }

    // lane ml==0 writes component 0, ml==1 writes component 1
    if (ml < 2) {
        float bb = 2.f * b3[ml];
#pragma unroll
        for (int reg = 0; reg < 4; ++reg) {
            int ee = blockIdx.x * 128 + wv * 16 + quad * 4 + reg;
            if (ee < E) {
                float v = (ml == 0) ? p0[reg] : p1[reg];
                out[(size_t)ee * 2 + ml] = v + bb;
            }
        }
    }
}

// ---------------------------------------------------------------------------
extern "C" void kernel_launch(void* const* d_in, const int* in_sizes, int n_in,
                              void* d_out, int out_size, void* d_ws, size_t ws_size,
                              hipStream_t stream) {
    (void)n_in; (void)out_size; (void)ws_size;
    const float* h  = (const float*)d_in[0];
    const int*   sr = (const int*)d_in[1];
    const int*   ds = (const int*)d_in[2];
    const float* W1 = (const float*)d_in[3];
    const float* b1 = (const float*)d_in[4];
    const float* W2 = (const float*)d_in[5];
    const float* b2 = (const float*)d_in[6];
    const float* W3 = (const float*)d_in[7];
    const float* b3 = (const float*)d_in[8];
    float* out = (float*)d_out;

    int E = in_sizes[1];

    unsigned short* W1c = (unsigned short*)d_ws;          // 128*256
    unsigned short* W2t = W1c + 128 * 256;                // 128*128

    prep_weights<<<(128 * 256 + 128 * 128 + 255) / 256, 256, 0, stream>>>(W1, W2, W1c, W2t);

    int etiles = (E + 127) / 128;
    edge_fused<<<etiles, 512, 0, stream>>>(h, sr, ds, W1c, W2t, b1, b2, W3, b3, out, E);
}